// Round 1
// baseline (1836.420 us; speedup 1.0000x reference)
//
#include <hip/hip_runtime.h>

#define N_NODES 50000
#define N_EDGES 800000
#define N_GRAPH 1000

// ---------------- layer GEMM: A[N,128] @ W[128,128] -> out[N,128] ----------------
__global__ __launch_bounds__(256) void gemm128(const float* __restrict__ A,
                                               const float* __restrict__ W,
                                               float* __restrict__ out, int nrows) {
    __shared__ float sA[16][68];    // [kk][row], padded
    __shared__ float sB[16][132];   // [kk][col], padded
    const int tid = threadIdx.x;
    const int tx = tid & 15, ty = tid >> 4;
    const int n0 = blockIdx.x * 64;
    float acc[4][8];
#pragma unroll
    for (int i = 0; i < 4; i++)
#pragma unroll
        for (int j = 0; j < 8; j++) acc[i][j] = 0.f;

    const int lrow = tid >> 2;   // 0..63
    const int lq   = tid & 3;    // k-chunk of 4

    for (int k0 = 0; k0 < 128; k0 += 16) {
        __syncthreads();
        // A tile (64 rows x 16 k), stored transposed
        float4 av = make_float4(0.f, 0.f, 0.f, 0.f);
        int gr = n0 + lrow;
        if (gr < nrows) av = *(const float4*)(A + (size_t)gr * 128 + k0 + lq * 4);
        sA[lq * 4 + 0][lrow] = av.x;
        sA[lq * 4 + 1][lrow] = av.y;
        sA[lq * 4 + 2][lrow] = av.z;
        sA[lq * 4 + 3][lrow] = av.w;
        // B tile (16 k x 128 cols)
        {
            int krow = tid >> 4;
            int bc = (tid & 15) * 8;
            const float* wp = W + (size_t)(k0 + krow) * 128 + bc;
            *(float4*)&sB[krow][bc]     = *(const float4*)(wp);
            *(float4*)&sB[krow][bc + 4] = *(const float4*)(wp + 4);
        }
        __syncthreads();
#pragma unroll
        for (int kk = 0; kk < 16; kk++) {
            float a[4], b[8];
#pragma unroll
            for (int i = 0; i < 4; i++) a[i] = sA[kk][ty * 4 + i];
#pragma unroll
            for (int j = 0; j < 8; j++) b[j] = sB[kk][tx * 8 + j];
#pragma unroll
            for (int i = 0; i < 4; i++)
#pragma unroll
                for (int j = 0; j < 8; j++) acc[i][j] += a[i] * b[j];
        }
    }
#pragma unroll
    for (int i = 0; i < 4; i++) {
        int gr = n0 + ty * 4 + i;
        if (gr < nrows) {
            float* op = out + (size_t)gr * 128 + tx * 8;
            *(float4*)(op)     = make_float4(acc[i][0], acc[i][1], acc[i][2], acc[i][3]);
            *(float4*)(op + 4) = make_float4(acc[i][4], acc[i][5], acc[i][6], acc[i][7]);
        }
    }
}

// ---------------- per-node attention coefficients ----------------
__global__ void node_al(const float* __restrict__ xs, const float* __restrict__ a_s,
                        const float* __restrict__ a_d, float* __restrict__ alsrc,
                        float* __restrict__ aldst, int n) {
    int t = blockIdx.x * blockDim.x + threadIdx.x;
    if (t >= n * 8) return;
    int node = t >> 3, h = t & 7;
    const float4* xp = (const float4*)(xs + (size_t)node * 128 + h * 16);
    const float4* sp = (const float4*)(a_s + h * 16);
    const float4* dp = (const float4*)(a_d + h * 16);
    float ss = 0.f, dd = 0.f;
#pragma unroll
    for (int q = 0; q < 4; q++) {
        float4 x4 = xp[q], s4 = sp[q], d4 = dp[q];
        ss += x4.x * s4.x + x4.y * s4.y + x4.z * s4.z + x4.w * s4.w;
        dd += x4.x * d4.x + x4.y * d4.y + x4.z * d4.z + x4.w * d4.w;
    }
    alsrc[t] = ss;
    aldst[t] = dd;
}

// ---------------- aeW[k][h] = sum_c We[k, h*16+c] * ae[h,c] ----------------
__global__ void aew_k(const float* __restrict__ We, const float* __restrict__ ae,
                      float* __restrict__ aeW) {
    int t = threadIdx.x;   // 128 threads
    int k = t >> 3, h = t & 7;
    float s = 0.f;
#pragma unroll
    for (int c = 0; c < 16; c++) s += We[k * 128 + h * 16 + c] * ae[h * 16 + c];
    aeW[k * 8 + h] = s;
}

// ---------------- edge pass: one wave per edge ----------------
// accumulates denom[dst,h] += ex  and  hout[dst,:] += ex * xs[src,:]
__global__ __launch_bounds__(256) void edge_k(const int* __restrict__ ei,
                                              const float* __restrict__ eattr,
                                              const float* __restrict__ alsrc,
                                              const float* __restrict__ aldst,
                                              const float* __restrict__ aeW,
                                              const float* __restrict__ xs,
                                              float* __restrict__ denom,
                                              float* __restrict__ hout, int ne) {
    __shared__ float sAe[128];
    if (threadIdx.x < 128) sAe[threadIdx.x] = aeW[threadIdx.x];
    __syncthreads();
    int e = blockIdx.x * 4 + (threadIdx.x >> 6);
    int lane = threadIdx.x & 63;
    if (e >= ne) return;
    int src = ei[e];
    int dst = ei[ne + e];
    float eav = (lane < 16) ? eattr[(size_t)e * 16 + lane] : 0.f;
    int h = lane & 7;   // lanes 0..7 are the authoritative per-head lanes
    float lg = alsrc[src * 8 + h] + aldst[dst * 8 + h];
#pragma unroll
    for (int k = 0; k < 16; k++) lg += __shfl(eav, k) * sAe[k * 8 + h];
    lg = lg > 0.f ? lg : 0.2f * lg;        // leaky_relu(0.2)
    float ex = expf(lg);
    if (lane < 8) atomicAdd(denom + (size_t)dst * 8 + h, ex);
    // channels: lane -> c=lane (head lane>>4), c=lane+64 (head lane>>4 + 4)
    float ex1 = __shfl(ex, lane >> 4);
    float ex2 = __shfl(ex, (lane >> 4) + 4);
    const float* xp = xs + (size_t)src * 128;
    float* op = hout + (size_t)dst * 128;
    atomicAdd(op + lane,      xp[lane]      * ex1);
    atomicAdd(op + lane + 64, xp[lane + 64] * ex2);
}

// ---------------- normalize + bias ----------------
__global__ void norm_k(float* __restrict__ h, const float* __restrict__ denom,
                       const float* __restrict__ b, int n) {
    int t = blockIdx.x * blockDim.x + threadIdx.x;
    if (t >= n * 128) return;
    int node = t >> 7, j = t & 127;
    h[t] = h[t] / (denom[node * 8 + (j >> 4)] + 1e-16f) + b[j];
}

// ---------------- global add pool ----------------
__global__ void pool_k(const float* __restrict__ h3, const int* __restrict__ batch,
                       float* __restrict__ pool, int n) {
    int t = blockIdx.x * blockDim.x + threadIdx.x;
    if (t >= n * 128) return;
    int node = t >> 7, j = t & 127;
    atomicAdd(pool + (size_t)batch[node] * 128 + j, h3[t]);
}

// ---------------- fused final MLP: out = leaky(H@Wl1+bl1, .01) @ Wl2 + bl2 ----------------
// H[n] = concat(h1[n], h2[n], h3[n], pool[batch[n]])  (512)
__global__ __launch_bounds__(256) void final_k(const float* __restrict__ h1,
                                               const float* __restrict__ h2,
                                               const float* __restrict__ h3,
                                               const float* __restrict__ pool,
                                               const int* __restrict__ batch,
                                               const float* __restrict__ Wl1,
                                               const float* __restrict__ bl1,
                                               const float* __restrict__ Wl2,
                                               const float* __restrict__ bl2,
                                               float* __restrict__ out, int nrows) {
    __shared__ float sA[16][68];
    __shared__ float sB[16][132];
    __shared__ float sW2[512];
    __shared__ float sB1[512];
    __shared__ float sRed[64][17];
    const int tid = threadIdx.x;
    const int tx = tid & 15, ty = tid >> 4;
    const int n0 = blockIdx.x * 64;
    sW2[tid] = Wl2[tid];  sW2[tid + 256] = Wl2[tid + 256];
    sB1[tid] = bl1[tid];  sB1[tid + 256] = bl1[tid + 256];

    float rowacc[4] = {0.f, 0.f, 0.f, 0.f};
    const int lrow = tid >> 2, lq = tid & 3;

    for (int j0 = 0; j0 < 512; j0 += 128) {
        float acc[4][8];
#pragma unroll
        for (int i = 0; i < 4; i++)
#pragma unroll
            for (int j = 0; j < 8; j++) acc[i][j] = 0.f;

        for (int k0 = 0; k0 < 512; k0 += 16) {
            __syncthreads();
            // assemble A tile from the concat segments
            float4 av = make_float4(0.f, 0.f, 0.f, 0.f);
            int gr = n0 + lrow;
            if (gr < nrows) {
                int seg = k0 >> 7;
                int col = (k0 & 127) + lq * 4;
                const float* ap;
                if (seg == 0)      ap = h1 + (size_t)gr * 128 + col;
                else if (seg == 1) ap = h2 + (size_t)gr * 128 + col;
                else if (seg == 2) ap = h3 + (size_t)gr * 128 + col;
                else               ap = pool + (size_t)batch[gr] * 128 + col;
                av = *(const float4*)ap;
            }
            sA[lq * 4 + 0][lrow] = av.x;
            sA[lq * 4 + 1][lrow] = av.y;
            sA[lq * 4 + 2][lrow] = av.z;
            sA[lq * 4 + 3][lrow] = av.w;
            // B tile: Wl1 rows k0..k0+15, cols j0..j0+127
            {
                int krow = tid >> 4;
                int bc = (tid & 15) * 8;
                const float* wp = Wl1 + (size_t)(k0 + krow) * 512 + j0 + bc;
                *(float4*)&sB[krow][bc]     = *(const float4*)(wp);
                *(float4*)&sB[krow][bc + 4] = *(const float4*)(wp + 4);
            }
            __syncthreads();
#pragma unroll
            for (int kk = 0; kk < 16; kk++) {
                float a[4], b[8];
#pragma unroll
                for (int i = 0; i < 4; i++) a[i] = sA[kk][ty * 4 + i];
#pragma unroll
                for (int j = 0; j < 8; j++) b[j] = sB[kk][tx * 8 + j];
#pragma unroll
                for (int i = 0; i < 4; i++)
#pragma unroll
                    for (int j = 0; j < 8; j++) acc[i][j] += a[i] * b[j];
            }
        }
        // epilogue for this j-tile: leaky + dot with Wl2
#pragma unroll
        for (int i = 0; i < 4; i++) {
#pragma unroll
            for (int j = 0; j < 8; j++) {
                int c = j0 + tx * 8 + j;
                float z = acc[i][j] + sB1[c];
                z = z > 0.f ? z : 0.01f * z;
                rowacc[i] += z * sW2[c];
            }
        }
    }
    __syncthreads();
#pragma unroll
    for (int i = 0; i < 4; i++) sRed[ty * 4 + i][tx] = rowacc[i];
    __syncthreads();
    if (tid < 64) {
        float s = 0.f;
#pragma unroll
        for (int x = 0; x < 16; x++) s += sRed[tid][x];
        int gr = n0 + tid;
        if (gr < nrows) out[gr] = s + bl2[0];
    }
}

extern "C" void kernel_launch(void* const* d_in, const int* in_sizes, int n_in,
                              void* d_out, int out_size, void* d_ws, size_t ws_size,
                              hipStream_t stream) {
    const float* x     = (const float*)d_in[0];
    const int*   ei    = (const int*)d_in[1];
    const float* eattr = (const float*)d_in[2];
    const int*   batch = (const int*)d_in[3];
    const float* W[3]   = {(const float*)d_in[4],  (const float*)d_in[10], (const float*)d_in[16]};
    const float* We[3]  = {(const float*)d_in[5],  (const float*)d_in[11], (const float*)d_in[17]};
    const float* as_[3] = {(const float*)d_in[6],  (const float*)d_in[12], (const float*)d_in[18]};
    const float* ad_[3] = {(const float*)d_in[7],  (const float*)d_in[13], (const float*)d_in[19]};
    const float* ae_[3] = {(const float*)d_in[8],  (const float*)d_in[14], (const float*)d_in[20]};
    const float* b_[3]  = {(const float*)d_in[9],  (const float*)d_in[15], (const float*)d_in[21]};
    const float* Wl1 = (const float*)d_in[22];
    const float* bl1 = (const float*)d_in[23];
    const float* Wl2 = (const float*)d_in[24];
    const float* bl2 = (const float*)d_in[25];

    const int N = N_NODES, E = N_EDGES, G = N_GRAPH;

    float* ws    = (float*)d_ws;
    float* xs    = ws;                          // N*128
    float* h0    = xs + (size_t)N * 128;        // N*128 (h1)
    float* h1b   = h0 + (size_t)N * 128;        // N*128 (h2)
    float* h2b   = h1b + (size_t)N * 128;       // N*128 (h3)
    float* hbuf[3] = {h0, h1b, h2b};
    float* alsrc = h2b + (size_t)N * 128;       // N*8
    float* aldst = alsrc + (size_t)N * 8;       // N*8
    float* denom = aldst + (size_t)N * 8;       // N*8
    float* pool  = denom + (size_t)N * 8;       // G*128
    float* aeW   = pool + (size_t)G * 128;      // 16*8

    for (int l = 0; l < 3; l++) {
        hipMemsetAsync(denom, 0, (size_t)N * 8 * sizeof(float), stream);
        hipMemsetAsync(hbuf[l], 0, (size_t)N * 128 * sizeof(float), stream);
        const float* Ain = (l == 0) ? x : hbuf[l - 1];
        gemm128<<<(N + 63) / 64, 256, 0, stream>>>(Ain, W[l], xs, N);
        node_al<<<(N * 8 + 255) / 256, 256, 0, stream>>>(xs, as_[l], ad_[l], alsrc, aldst, N);
        aew_k<<<1, 128, 0, stream>>>(We[l], ae_[l], aeW);
        edge_k<<<(E + 3) / 4, 256, 0, stream>>>(ei, eattr, alsrc, aldst, aeW, xs, denom, hbuf[l], E);
        norm_k<<<(N * 128 + 255) / 256, 256, 0, stream>>>(hbuf[l], denom, b_[l], N);
    }
    hipMemsetAsync(pool, 0, (size_t)G * 128 * sizeof(float), stream);
    pool_k<<<(N * 128 + 255) / 256, 256, 0, stream>>>(hbuf[2], batch, pool, N);
    final_k<<<(N + 63) / 64, 256, 0, stream>>>(hbuf[0], hbuf[1], hbuf[2], pool, batch,
                                               Wl1, bl1, Wl2, bl2, (float*)d_out, N);
}

// Round 2
// 1428.051 us; speedup vs baseline: 1.2860x; 1.2860x over previous
//
#include <hip/hip_runtime.h>

#define N_NODES 50000
#define N_EDGES 800000
#define N_GRAPH 1000

typedef short bf16x8 __attribute__((ext_vector_type(8)));
typedef float f32x4 __attribute__((ext_vector_type(4)));

__device__ inline short f2b(float f) {   // f32 -> bf16 (RNE)
    union { float f; unsigned u; } x; x.f = f;
    unsigned r = x.u + 0x7FFF + ((x.u >> 16) & 1);
    return (short)(r >> 16);
}

// ---------------- layer GEMM: A[N,128] @ W[128,128] -> out[N,128] (f32) ----------------
__global__ __launch_bounds__(256) void gemm128(const float* __restrict__ A,
                                               const float* __restrict__ W,
                                               float* __restrict__ out, int nrows) {
    __shared__ float sA[16][68];    // [kk][row], padded
    __shared__ float sB[16][132];   // [kk][col], padded
    const int tid = threadIdx.x;
    const int tx = tid & 15, ty = tid >> 4;
    const int n0 = blockIdx.x * 64;
    float acc[4][8];
#pragma unroll
    for (int i = 0; i < 4; i++)
#pragma unroll
        for (int j = 0; j < 8; j++) acc[i][j] = 0.f;

    const int lrow = tid >> 2;   // 0..63
    const int lq   = tid & 3;    // k-chunk of 4

    for (int k0 = 0; k0 < 128; k0 += 16) {
        __syncthreads();
        float4 av = make_float4(0.f, 0.f, 0.f, 0.f);
        int gr = n0 + lrow;
        if (gr < nrows) av = *(const float4*)(A + (size_t)gr * 128 + k0 + lq * 4);
        sA[lq * 4 + 0][lrow] = av.x;
        sA[lq * 4 + 1][lrow] = av.y;
        sA[lq * 4 + 2][lrow] = av.z;
        sA[lq * 4 + 3][lrow] = av.w;
        {
            int krow = tid >> 4;
            int bc = (tid & 15) * 8;
            const float* wp = W + (size_t)(k0 + krow) * 128 + bc;
            *(float4*)&sB[krow][bc]     = *(const float4*)(wp);
            *(float4*)&sB[krow][bc + 4] = *(const float4*)(wp + 4);
        }
        __syncthreads();
#pragma unroll
        for (int kk = 0; kk < 16; kk++) {
            float a[4], b[8];
#pragma unroll
            for (int i = 0; i < 4; i++) a[i] = sA[kk][ty * 4 + i];
#pragma unroll
            for (int j = 0; j < 8; j++) b[j] = sB[kk][tx * 8 + j];
#pragma unroll
            for (int i = 0; i < 4; i++)
#pragma unroll
                for (int j = 0; j < 8; j++) acc[i][j] += a[i] * b[j];
        }
    }
#pragma unroll
    for (int i = 0; i < 4; i++) {
        int gr = n0 + ty * 4 + i;
        if (gr < nrows) {
            float* op = out + (size_t)gr * 128 + tx * 8;
            *(float4*)(op)     = make_float4(acc[i][0], acc[i][1], acc[i][2], acc[i][3]);
            *(float4*)(op + 4) = make_float4(acc[i][4], acc[i][5], acc[i][6], acc[i][7]);
        }
    }
}

// ---------------- per-node attention coefficients ----------------
__global__ void node_al(const float* __restrict__ xs, const float* __restrict__ a_s,
                        const float* __restrict__ a_d, float* __restrict__ alsrc,
                        float* __restrict__ aldst, int n) {
    int t = blockIdx.x * blockDim.x + threadIdx.x;
    if (t >= n * 8) return;
    int node = t >> 3, h = t & 7;
    const float4* xp = (const float4*)(xs + (size_t)node * 128 + h * 16);
    const float4* sp = (const float4*)(a_s + h * 16);
    const float4* dp = (const float4*)(a_d + h * 16);
    float ss = 0.f, dd = 0.f;
#pragma unroll
    for (int q = 0; q < 4; q++) {
        float4 x4 = xp[q], s4 = sp[q], d4 = dp[q];
        ss += x4.x * s4.x + x4.y * s4.y + x4.z * s4.z + x4.w * s4.w;
        dd += x4.x * d4.x + x4.y * d4.y + x4.z * d4.z + x4.w * d4.w;
    }
    alsrc[t] = ss;
    aldst[t] = dd;
}

// ---------------- aeW[k][h] = sum_c We[k, h*16+c] * ae[h,c] ----------------
__global__ void aew_k(const float* __restrict__ We, const float* __restrict__ ae,
                      float* __restrict__ aeW) {
    int t = threadIdx.x;   // 128 threads
    int k = t >> 3, h = t & 7;
    float s = 0.f;
#pragma unroll
    for (int c = 0; c < 16; c++) s += We[k * 128 + h * 16 + c] * ae[h * 16 + c];
    aeW[k * 8 + h] = s;
}

// ---------------- edge pass: one wave per edge ----------------
__global__ __launch_bounds__(256) void edge_k(const int* __restrict__ ei,
                                              const float* __restrict__ eattr,
                                              const float* __restrict__ alsrc,
                                              const float* __restrict__ aldst,
                                              const float* __restrict__ aeW,
                                              const float* __restrict__ xs,
                                              float* __restrict__ denom,
                                              float* __restrict__ hout, int ne) {
    __shared__ float sAe[128];
    if (threadIdx.x < 128) sAe[threadIdx.x] = aeW[threadIdx.x];
    __syncthreads();
    int e = blockIdx.x * 4 + (threadIdx.x >> 6);
    int lane = threadIdx.x & 63;
    if (e >= ne) return;
    int src = ei[e];
    int dst = ei[ne + e];
    float eav = (lane < 16) ? eattr[(size_t)e * 16 + lane] : 0.f;
    int h = lane & 7;
    float lg = alsrc[src * 8 + h] + aldst[dst * 8 + h];
#pragma unroll
    for (int k = 0; k < 16; k++) lg += __shfl(eav, k) * sAe[k * 8 + h];
    lg = lg > 0.f ? lg : 0.2f * lg;        // leaky_relu(0.2)
    float ex = expf(lg);
    if (lane < 8) atomicAdd(denom + (size_t)dst * 8 + h, ex);
    float ex1 = __shfl(ex, lane >> 4);
    float ex2 = __shfl(ex, (lane >> 4) + 4);
    const float* xp = xs + (size_t)src * 128;
    float* op = hout + (size_t)dst * 128;
    atomicAdd(op + lane,      xp[lane]      * ex1);
    atomicAdd(op + lane + 64, xp[lane + 64] * ex2);
}

// ---------------- normalize + bias ----------------
__global__ void norm_k(float* __restrict__ h, const float* __restrict__ denom,
                       const float* __restrict__ b, int n) {
    int t = blockIdx.x * blockDim.x + threadIdx.x;
    if (t >= n * 128) return;
    int node = t >> 7, j = t & 127;
    h[t] = h[t] / (denom[node * 8 + (j >> 4)] + 1e-16f) + b[j];
}

// ---------------- global add pool ----------------
__global__ void pool_k(const float* __restrict__ h3, const int* __restrict__ batch,
                       float* __restrict__ pool, int n) {
    int t = blockIdx.x * blockDim.x + threadIdx.x;
    if (t >= n * 128) return;
    int node = t >> 7, j = t & 127;
    atomicAdd(pool + (size_t)batch[node] * 128 + j, h3[t]);
}

// ---------------- Wl1 [512(k),512(c)] f32 -> Wl1T [c][k] bf16 ----------------
__global__ void wl1t_k(const float* __restrict__ Wl1, short* __restrict__ Wl1T) {
    int idx = blockIdx.x * blockDim.x + threadIdx.x;   // 262144
    int k = idx >> 9, c = idx & 511;
    Wl1T[(size_t)c * 512 + k] = f2b(Wl1[idx]);
}

// ---------------- out[n] = bl2 (atomic partials added later) ----------------
__global__ void init_out(float* __restrict__ out, const float* __restrict__ bl2, int n) {
    int t = blockIdx.x * blockDim.x + threadIdx.x;
    if (t < n) out[t] = bl2[0];
}

// ---------------- fused final MLP via bf16 MFMA ----------------
// Z = concat(h1,h2,h3,pool[batch]) @ Wl1 + bl1 ; out += leaky(Z,.01) @ Wl2
// BM=64 rows/block, BN=256 cols (grid.y=2), BK=32. 4 waves, each 64x64.
__global__ __launch_bounds__(256) void final_mfma(
    const float* __restrict__ h1, const float* __restrict__ h2,
    const float* __restrict__ h3, const float* __restrict__ pool,
    const int* __restrict__ batch, const short* __restrict__ Wl1T,
    const float* __restrict__ bl1, const float* __restrict__ Wl2,
    float* __restrict__ out, int nrows)
{
    __shared__ short Abuf[64 * 40];    // [row][k], rows padded to 40 (80 B)
    __shared__ short Bbuf[256 * 40];   // [col][k], padded
    __shared__ int   sBatch[64];
    const int tid = threadIdx.x;
    const int n0 = blockIdx.x * 64;
    const int j0 = blockIdx.y * 256;
    const int wid = tid >> 6, lane = tid & 63;
    const int lr = lane & 15, kg = lane >> 4;

    if (tid < 64) {
        int gr = n0 + tid;
        sBatch[tid] = (gr < nrows) ? batch[gr] : 0;
    }
    // epilogue constants for this thread's 4 column groups
    float w2[4], b1c[4];
#pragma unroll
    for (int fn = 0; fn < 4; fn++) {
        int c = j0 + wid * 64 + fn * 16 + lr;
        w2[fn]  = Wl2[c];
        b1c[fn] = bl1[c];
    }

    f32x4 acc[4][4] = {};

    for (int k0 = 0; k0 < 512; k0 += 32) {
        const int seg = k0 >> 7;
        const float* base = (seg == 0) ? h1 : (seg == 1) ? h2 : (seg == 2) ? h3 : pool;
        const int cseg = k0 & 127;
        __syncthreads();   // LDS free (also covers sBatch on first iter)
        // stage A: 64 rows x 32 k, f32 -> bf16 on the fly
#pragma unroll
        for (int i = 0; i < 2; i++) {
            int idx = tid + i * 256;      // 0..511
            int row = idx >> 3;           // 0..63
            int slot = idx & 7;           // 8 float4 slots per 32-f32 row
            float4 v = make_float4(0.f, 0.f, 0.f, 0.f);
            int gr = n0 + row;
            if (gr < nrows) {
                int grow = (seg == 3) ? sBatch[row] : gr;
                v = *(const float4*)(base + (size_t)grow * 128 + cseg + slot * 4);
            }
            *(short4*)(&Abuf[row * 40 + slot * 4]) =
                make_short4(f2b(v.x), f2b(v.y), f2b(v.z), f2b(v.w));
        }
        // stage B: 256 cols x 32 k, already bf16 (k-contiguous in Wl1T)
#pragma unroll
        for (int i = 0; i < 4; i++) {
            int idx = tid + i * 256;      // 0..1023
            int c = idx >> 2, slot = idx & 3;
            uint4 v = *(const uint4*)(Wl1T + (size_t)(j0 + c) * 512 + k0 + slot * 8);
            *(uint4*)(&Bbuf[c * 40 + slot * 8]) = v;
        }
        __syncthreads();
        // fragments + MFMA
        bf16x8 a[4], b[4];
#pragma unroll
        for (int fm = 0; fm < 4; fm++)
            a[fm] = *(const bf16x8*)(&Abuf[(fm * 16 + lr) * 40 + kg * 8]);
#pragma unroll
        for (int fn = 0; fn < 4; fn++)
            b[fn] = *(const bf16x8*)(&Bbuf[(wid * 64 + fn * 16 + lr) * 40 + kg * 8]);
#pragma unroll
        for (int fm = 0; fm < 4; fm++)
#pragma unroll
            for (int fn = 0; fn < 4; fn++)
                acc[fm][fn] = __builtin_amdgcn_mfma_f32_16x16x32_bf16(
                    a[fm], b[fn], acc[fm][fn], 0, 0, 0);
    }

    // epilogue: leaky + dot(Wl2) over this block's 256 cols, reduce, atomic add
#pragma unroll
    for (int fm = 0; fm < 4; fm++) {
#pragma unroll
        for (int r = 0; r < 4; r++) {
            float s = 0.f;
#pragma unroll
            for (int fn = 0; fn < 4; fn++) {
                float z = acc[fm][fn][r] + b1c[fn];
                z = z > 0.f ? z : 0.01f * z;
                s += z * w2[fn];
            }
            s += __shfl_xor(s, 1);
            s += __shfl_xor(s, 2);
            s += __shfl_xor(s, 4);
            s += __shfl_xor(s, 8);
            if (lr == 0) {
                int gr = n0 + fm * 16 + kg * 4 + r;
                if (gr < nrows) atomicAdd(out + gr, s);
            }
        }
    }
}

extern "C" void kernel_launch(void* const* d_in, const int* in_sizes, int n_in,
                              void* d_out, int out_size, void* d_ws, size_t ws_size,
                              hipStream_t stream) {
    const float* x     = (const float*)d_in[0];
    const int*   ei    = (const int*)d_in[1];
    const float* eattr = (const float*)d_in[2];
    const int*   batch = (const int*)d_in[3];
    const float* W[3]   = {(const float*)d_in[4],  (const float*)d_in[10], (const float*)d_in[16]};
    const float* We[3]  = {(const float*)d_in[5],  (const float*)d_in[11], (const float*)d_in[17]};
    const float* as_[3] = {(const float*)d_in[6],  (const float*)d_in[12], (const float*)d_in[18]};
    const float* ad_[3] = {(const float*)d_in[7],  (const float*)d_in[13], (const float*)d_in[19]};
    const float* ae_[3] = {(const float*)d_in[8],  (const float*)d_in[14], (const float*)d_in[20]};
    const float* b_[3]  = {(const float*)d_in[9],  (const float*)d_in[15], (const float*)d_in[21]};
    const float* Wl1 = (const float*)d_in[22];
    const float* bl1 = (const float*)d_in[23];
    const float* Wl2 = (const float*)d_in[24];
    const float* bl2 = (const float*)d_in[25];

    const int N = N_NODES, E = N_EDGES, G = N_GRAPH;

    float* ws    = (float*)d_ws;
    float* xs    = ws;                          // N*128
    float* h0    = xs + (size_t)N * 128;        // N*128 (h1)
    float* h1b   = h0 + (size_t)N * 128;        // N*128 (h2)
    float* h2b   = h1b + (size_t)N * 128;       // N*128 (h3)
    float* hbuf[3] = {h0, h1b, h2b};
    float* alsrc = h2b + (size_t)N * 128;       // N*8
    float* aldst = alsrc + (size_t)N * 8;       // N*8
    float* denom = aldst + (size_t)N * 8;       // N*8
    float* pool  = denom + (size_t)N * 8;       // G*128
    float* aeW   = pool + (size_t)G * 128;      // 128
    short* wl1t  = (short*)(aeW + 128);         // 512*512 bf16 (16B-aligned)

    wl1t_k<<<1024, 256, 0, stream>>>(Wl1, wl1t);

    for (int l = 0; l < 3; l++) {
        hipMemsetAsync(denom, 0, (size_t)N * 8 * sizeof(float), stream);
        hipMemsetAsync(hbuf[l], 0, (size_t)N * 128 * sizeof(float), stream);
        const float* Ain = (l == 0) ? x : hbuf[l - 1];
        gemm128<<<(N + 63) / 64, 256, 0, stream>>>(Ain, W[l], xs, N);
        node_al<<<(N * 8 + 255) / 256, 256, 0, stream>>>(xs, as_[l], ad_[l], alsrc, aldst, N);
        aew_k<<<1, 128, 0, stream>>>(We[l], ae_[l], aeW);
        edge_k<<<(E + 3) / 4, 256, 0, stream>>>(ei, eattr, alsrc, aldst, aeW, xs, denom, hbuf[l], E);
        norm_k<<<(N * 128 + 255) / 256, 256, 0, stream>>>(hbuf[l], denom, b_[l], N);
    }
    hipMemsetAsync(pool, 0, (size_t)G * 128 * sizeof(float), stream);
    pool_k<<<(N * 128 + 255) / 256, 256, 0, stream>>>(hbuf[2], batch, pool, N);

    init_out<<<(N + 255) / 256, 256, 0, stream>>>((float*)d_out, bl2, N);
    dim3 fg((N + 63) / 64, 2);
    final_mfma<<<fg, 256, 0, stream>>>(hbuf[0], hbuf[1], hbuf[2], pool, batch,
                                       wl1t, bl1, Wl2, (float*)d_out, N);
}

// Round 3
// 673.316 us; speedup vs baseline: 2.7274x; 2.1209x over previous
//
#include <hip/hip_runtime.h>

#define N_NODES 50000
#define N_EDGES 800000
#define N_GRAPH 1000

typedef short bf16x8 __attribute__((ext_vector_type(8)));
typedef float f32x4 __attribute__((ext_vector_type(4)));

__device__ inline short f2b(float f) {   // f32 -> bf16 (RNE)
    union { float f; unsigned u; } x; x.f = f;
    unsigned r = x.u + 0x7FFF + ((x.u >> 16) & 1);
    return (short)(r >> 16);
}

// ---------------- layer GEMM: A[N,128] @ W[128,128] -> out[N,128] (f32) ----------------
__global__ __launch_bounds__(256) void gemm128(const float* __restrict__ A,
                                               const float* __restrict__ W,
                                               float* __restrict__ out, int nrows) {
    __shared__ float sA[16][68];
    __shared__ float sB[16][132];
    const int tid = threadIdx.x;
    const int tx = tid & 15, ty = tid >> 4;
    const int n0 = blockIdx.x * 64;
    float acc[4][8];
#pragma unroll
    for (int i = 0; i < 4; i++)
#pragma unroll
        for (int j = 0; j < 8; j++) acc[i][j] = 0.f;

    const int lrow = tid >> 2;
    const int lq   = tid & 3;

    for (int k0 = 0; k0 < 128; k0 += 16) {
        __syncthreads();
        float4 av = make_float4(0.f, 0.f, 0.f, 0.f);
        int gr = n0 + lrow;
        if (gr < nrows) av = *(const float4*)(A + (size_t)gr * 128 + k0 + lq * 4);
        sA[lq * 4 + 0][lrow] = av.x;
        sA[lq * 4 + 1][lrow] = av.y;
        sA[lq * 4 + 2][lrow] = av.z;
        sA[lq * 4 + 3][lrow] = av.w;
        {
            int krow = tid >> 4;
            int bc = (tid & 15) * 8;
            const float* wp = W + (size_t)(k0 + krow) * 128 + bc;
            *(float4*)&sB[krow][bc]     = *(const float4*)(wp);
            *(float4*)&sB[krow][bc + 4] = *(const float4*)(wp + 4);
        }
        __syncthreads();
#pragma unroll
        for (int kk = 0; kk < 16; kk++) {
            float a[4], b[8];
#pragma unroll
            for (int i = 0; i < 4; i++) a[i] = sA[kk][ty * 4 + i];
#pragma unroll
            for (int j = 0; j < 8; j++) b[j] = sB[kk][tx * 8 + j];
#pragma unroll
            for (int i = 0; i < 4; i++)
#pragma unroll
                for (int j = 0; j < 8; j++) acc[i][j] += a[i] * b[j];
        }
    }
#pragma unroll
    for (int i = 0; i < 4; i++) {
        int gr = n0 + ty * 4 + i;
        if (gr < nrows) {
            float* op = out + (size_t)gr * 128 + tx * 8;
            *(float4*)(op)     = make_float4(acc[i][0], acc[i][1], acc[i][2], acc[i][3]);
            *(float4*)(op + 4) = make_float4(acc[i][4], acc[i][5], acc[i][6], acc[i][7]);
        }
    }
}

// ---------------- per-node attention coefficients ----------------
__global__ void node_al(const float* __restrict__ xs, const float* __restrict__ a_s,
                        const float* __restrict__ a_d, float* __restrict__ alsrc,
                        float* __restrict__ aldst, int n) {
    int t = blockIdx.x * blockDim.x + threadIdx.x;
    if (t >= n * 8) return;
    int node = t >> 3, h = t & 7;
    const float4* xp = (const float4*)(xs + (size_t)node * 128 + h * 16);
    const float4* sp = (const float4*)(a_s + h * 16);
    const float4* dp = (const float4*)(a_d + h * 16);
    float ss = 0.f, dd = 0.f;
#pragma unroll
    for (int q = 0; q < 4; q++) {
        float4 x4 = xp[q], s4 = sp[q], d4 = dp[q];
        ss += x4.x * s4.x + x4.y * s4.y + x4.z * s4.z + x4.w * s4.w;
        dd += x4.x * d4.x + x4.y * d4.y + x4.z * d4.z + x4.w * d4.w;
    }
    alsrc[t] = ss;
    aldst[t] = dd;
}

// ---------------- aeW[k][h] = sum_c We[k, h*16+c] * ae[h,c] ----------------
__global__ void aew_k(const float* __restrict__ We, const float* __restrict__ ae,
                      float* __restrict__ aeW) {
    int t = threadIdx.x;   // 128 threads
    int k = t >> 3, h = t & 7;
    float s = 0.f;
#pragma unroll
    for (int c = 0; c < 16; c++) s += We[k * 128 + h * 16 + c] * ae[h * 16 + c];
    aeW[k * 8 + h] = s;
}

// ---------------- CSR build ----------------
__global__ void hist_k(const int* __restrict__ ei, int* __restrict__ cnt, int ne) {
    int e = blockIdx.x * blockDim.x + threadIdx.x;
    if (e < ne) atomicAdd(&cnt[ei[ne + e]], 1);
}

// block-wise exclusive scan, writes partial sums
__global__ void scan1_k(const int* __restrict__ cnt, int* __restrict__ rowptr,
                        int* __restrict__ part, int n) {
    __shared__ int s[256];
    int tid = threadIdx.x;
    int i = blockIdx.x * 256 + tid;
    int v = (i < n) ? cnt[i] : 0;
    s[tid] = v; __syncthreads();
#pragma unroll
    for (int off = 1; off < 256; off <<= 1) {
        int t = (tid >= off) ? s[tid - off] : 0;
        __syncthreads();
        s[tid] += t;
        __syncthreads();
    }
    if (i < n) rowptr[i] = s[tid] - v;
    if (tid == 255) part[blockIdx.x] = s[255];
}

__global__ void scan2_k(int* __restrict__ part, int npart) {
    __shared__ int s[256];
    int tid = threadIdx.x;
    int v = (tid < npart) ? part[tid] : 0;
    s[tid] = v; __syncthreads();
#pragma unroll
    for (int off = 1; off < 256; off <<= 1) {
        int t = (tid >= off) ? s[tid - off] : 0;
        __syncthreads();
        s[tid] += t;
        __syncthreads();
    }
    if (tid < npart) part[tid] = s[tid] - v;
}

__global__ void scan3_k(int* __restrict__ rowptr, const int* __restrict__ part,
                        int* __restrict__ cursor, int n, int ne) {
    int i = blockIdx.x * 256 + threadIdx.x;
    if (i < n) {
        int r = rowptr[i] + part[blockIdx.x];
        rowptr[i] = r;
        cursor[i] = r;
    }
    if (i == 0) rowptr[n] = ne;
}

__global__ void scatter_k(const int* __restrict__ ei, int* __restrict__ cursor,
                          int* __restrict__ pos, int* __restrict__ csr_src, int ne) {
    int e = blockIdx.x * blockDim.x + threadIdx.x;
    if (e >= ne) return;
    int d = ei[ne + e];
    int p = atomicAdd(&cursor[d], 1);
    pos[e] = p;
    csr_src[p] = ei[e];
}

// ---------------- per-edge logits (alsrc + al_e), written in CSR order ----------------
__global__ __launch_bounds__(256) void ale_k(const int* __restrict__ ei,
                                             const float* __restrict__ eattr,
                                             const float* __restrict__ alsrc,
                                             const float* __restrict__ aeW,
                                             const int* __restrict__ pos,
                                             float* __restrict__ ale_csr, int ne) {
    __shared__ float sAe[128];
    if (threadIdx.x < 128) sAe[threadIdx.x] = aeW[threadIdx.x];
    __syncthreads();
    int e = blockIdx.x * blockDim.x + threadIdx.x;
    if (e >= ne) return;
    float ea[16];
    const float4* ep = (const float4*)(eattr + (size_t)e * 16);
#pragma unroll
    for (int q = 0; q < 4; q++) {
        float4 v = ep[q];
        ea[q * 4 + 0] = v.x; ea[q * 4 + 1] = v.y; ea[q * 4 + 2] = v.z; ea[q * 4 + 3] = v.w;
    }
    int s = ei[e];
    float out[8];
#pragma unroll
    for (int h = 0; h < 8; h++) out[h] = alsrc[s * 8 + h];
#pragma unroll
    for (int k = 0; k < 16; k++)
#pragma unroll
        for (int h = 0; h < 8; h++) out[h] += ea[k] * sAe[k * 8 + h];
    float* op = ale_csr + (size_t)pos[e] * 8;
#pragma unroll
    for (int h = 0; h < 8; h++) op[h] = out[h];
}

// ---------------- gather: one wave per dst node; fuses softmax-normalize + bias ----------------
__global__ __launch_bounds__(256) void gather_k(const int* __restrict__ rowptr,
                                                const int* __restrict__ csr_src,
                                                const float* __restrict__ ale_csr,
                                                const float* __restrict__ aldst,
                                                const float* __restrict__ xs,
                                                const float* __restrict__ b,
                                                float* __restrict__ hout, int n) {
    int dst = blockIdx.x * 4 + (threadIdx.x >> 6);
    if (dst >= n) return;
    int lane = threadIdx.x & 63;
    int p0 = rowptr[dst], p1 = rowptr[dst + 1];
    float ald = aldst[dst * 8 + (lane & 7)];
    float den = 0.f, acc0 = 0.f, acc1 = 0.f;
    for (int p = p0; p < p1; ++p) {
        int s = csr_src[p];
        float al = (lane < 8) ? ale_csr[(size_t)p * 8 + lane] : 0.f;
        float lg = al + ald;
        lg = lg > 0.f ? lg : 0.2f * lg;       // leaky_relu(0.2)
        float ex = expf(lg);
        den += ex;                             // lanes 0..7 authoritative
        float ex1 = __shfl(ex, lane >> 4);
        float ex2 = __shfl(ex, (lane >> 4) + 4);
        const float* xp = xs + (size_t)s * 128;
        acc0 += xp[lane] * ex1;
        acc1 += xp[lane + 64] * ex2;
    }
    float d1 = __shfl(den, lane >> 4);
    float d2 = __shfl(den, (lane >> 4) + 4);
    float* op = hout + (size_t)dst * 128;
    op[lane]      = acc0 / (d1 + 1e-16f) + b[lane];
    op[lane + 64] = acc1 / (d2 + 1e-16f) + b[lane + 64];
}

// ---------------- global add pool ----------------
__global__ void pool_k(const float* __restrict__ h3, const int* __restrict__ batch,
                       float* __restrict__ pool, int n) {
    int t = blockIdx.x * blockDim.x + threadIdx.x;
    if (t >= n * 128) return;
    int node = t >> 7, j = t & 127;
    atomicAdd(pool + (size_t)batch[node] * 128 + j, h3[t]);
}

// ---------------- Wl1 [512(k),512(c)] f32 -> Wl1T [c][k] bf16 ----------------
__global__ void wl1t_k(const float* __restrict__ Wl1, short* __restrict__ Wl1T) {
    int idx = blockIdx.x * blockDim.x + threadIdx.x;   // 262144
    int k = idx >> 9, c = idx & 511;
    Wl1T[(size_t)c * 512 + k] = f2b(Wl1[idx]);
}

__global__ void init_out(float* __restrict__ out, const float* __restrict__ bl2, int n) {
    int t = blockIdx.x * blockDim.x + threadIdx.x;
    if (t < n) out[t] = bl2[0];
}

// ---------------- fused final MLP via bf16 MFMA ----------------
__global__ __launch_bounds__(256) void final_mfma(
    const float* __restrict__ h1, const float* __restrict__ h2,
    const float* __restrict__ h3, const float* __restrict__ pool,
    const int* __restrict__ batch, const short* __restrict__ Wl1T,
    const float* __restrict__ bl1, const float* __restrict__ Wl2,
    float* __restrict__ out, int nrows)
{
    __shared__ short Abuf[64 * 40];
    __shared__ short Bbuf[256 * 40];
    __shared__ int   sBatch[64];
    const int tid = threadIdx.x;
    const int n0 = blockIdx.x * 64;
    const int j0 = blockIdx.y * 256;
    const int wid = tid >> 6, lane = tid & 63;
    const int lr = lane & 15, kg = lane >> 4;

    if (tid < 64) {
        int gr = n0 + tid;
        sBatch[tid] = (gr < nrows) ? batch[gr] : 0;
    }
    float w2[4], b1c[4];
#pragma unroll
    for (int fn = 0; fn < 4; fn++) {
        int c = j0 + wid * 64 + fn * 16 + lr;
        w2[fn]  = Wl2[c];
        b1c[fn] = bl1[c];
    }

    f32x4 acc[4][4] = {};

    for (int k0 = 0; k0 < 512; k0 += 32) {
        const int seg = k0 >> 7;
        const float* base = (seg == 0) ? h1 : (seg == 1) ? h2 : (seg == 2) ? h3 : pool;
        const int cseg = k0 & 127;
        __syncthreads();
#pragma unroll
        for (int i = 0; i < 2; i++) {
            int idx = tid + i * 256;
            int row = idx >> 3;
            int slot = idx & 7;
            float4 v = make_float4(0.f, 0.f, 0.f, 0.f);
            int gr = n0 + row;
            if (gr < nrows) {
                int grow = (seg == 3) ? sBatch[row] : gr;
                v = *(const float4*)(base + (size_t)grow * 128 + cseg + slot * 4);
            }
            *(short4*)(&Abuf[row * 40 + slot * 4]) =
                make_short4(f2b(v.x), f2b(v.y), f2b(v.z), f2b(v.w));
        }
#pragma unroll
        for (int i = 0; i < 4; i++) {
            int idx = tid + i * 256;
            int c = idx >> 2, slot = idx & 3;
            uint4 v = *(const uint4*)(Wl1T + (size_t)(j0 + c) * 512 + k0 + slot * 8);
            *(uint4*)(&Bbuf[c * 40 + slot * 8]) = v;
        }
        __syncthreads();
        bf16x8 a[4], b[4];
#pragma unroll
        for (int fm = 0; fm < 4; fm++)
            a[fm] = *(const bf16x8*)(&Abuf[(fm * 16 + lr) * 40 + kg * 8]);
#pragma unroll
        for (int fn = 0; fn < 4; fn++)
            b[fn] = *(const bf16x8*)(&Bbuf[(wid * 64 + fn * 16 + lr) * 40 + kg * 8]);
#pragma unroll
        for (int fm = 0; fm < 4; fm++)
#pragma unroll
            for (int fn = 0; fn < 4; fn++)
                acc[fm][fn] = __builtin_amdgcn_mfma_f32_16x16x32_bf16(
                    a[fm], b[fn], acc[fm][fn], 0, 0, 0);
    }

#pragma unroll
    for (int fm = 0; fm < 4; fm++) {
#pragma unroll
        for (int r = 0; r < 4; r++) {
            float s = 0.f;
#pragma unroll
            for (int fn = 0; fn < 4; fn++) {
                float z = acc[fm][fn][r] + b1c[fn];
                z = z > 0.f ? z : 0.01f * z;
                s += z * w2[fn];
            }
            s += __shfl_xor(s, 1);
            s += __shfl_xor(s, 2);
            s += __shfl_xor(s, 4);
            s += __shfl_xor(s, 8);
            if (lr == 0) {
                int gr = n0 + fm * 16 + kg * 4 + r;
                if (gr < nrows) atomicAdd(out + gr, s);
            }
        }
    }
}

extern "C" void kernel_launch(void* const* d_in, const int* in_sizes, int n_in,
                              void* d_out, int out_size, void* d_ws, size_t ws_size,
                              hipStream_t stream) {
    const float* x     = (const float*)d_in[0];
    const int*   ei    = (const int*)d_in[1];
    const float* eattr = (const float*)d_in[2];
    const int*   batch = (const int*)d_in[3];
    const float* W[3]   = {(const float*)d_in[4],  (const float*)d_in[10], (const float*)d_in[16]};
    const float* We[3]  = {(const float*)d_in[5],  (const float*)d_in[11], (const float*)d_in[17]};
    const float* as_[3] = {(const float*)d_in[6],  (const float*)d_in[12], (const float*)d_in[18]};
    const float* ad_[3] = {(const float*)d_in[7],  (const float*)d_in[13], (const float*)d_in[19]};
    const float* ae_[3] = {(const float*)d_in[8],  (const float*)d_in[14], (const float*)d_in[20]};
    const float* b_[3]  = {(const float*)d_in[9],  (const float*)d_in[15], (const float*)d_in[21]};
    const float* Wl1 = (const float*)d_in[22];
    const float* bl1 = (const float*)d_in[23];
    const float* Wl2 = (const float*)d_in[24];
    const float* bl2 = (const float*)d_in[25];

    const int N = N_NODES, E = N_EDGES, G = N_GRAPH;

    float* ws    = (float*)d_ws;
    float* xs    = ws;                          // N*128
    float* h0    = xs + (size_t)N * 128;
    float* h1b   = h0 + (size_t)N * 128;
    float* h2b   = h1b + (size_t)N * 128;
    float* hbuf[3] = {h0, h1b, h2b};
    float* alsrc = h2b + (size_t)N * 128;       // N*8
    float* aldst = alsrc + (size_t)N * 8;       // N*8
    float* pool  = aldst + (size_t)N * 8;       // G*128
    float* aeW   = pool + (size_t)G * 128;      // 128
    float* ale   = aeW + 128;                   // E*8
    short* wl1t  = (short*)(ale + (size_t)E * 8);  // 512*512 bf16
    int*   cnt     = (int*)(wl1t + 512 * 512);  // N
    int*   rowptr  = cnt + N;                   // N+1
    int*   cursor  = rowptr + N + 1;            // N
    int*   part    = cursor + N;                // 256
    int*   pos     = part + 256;                // E
    int*   csr_src = pos + E;                   // E

    // ---- once per call: transpose Wl1, build dst-CSR ----
    wl1t_k<<<1024, 256, 0, stream>>>(Wl1, wl1t);
    hipMemsetAsync(cnt, 0, (size_t)N * sizeof(int), stream);
    hist_k<<<(E + 255) / 256, 256, 0, stream>>>(ei, cnt, E);
    const int nblk = (N + 255) / 256;   // 196
    scan1_k<<<nblk, 256, 0, stream>>>(cnt, rowptr, part, N);
    scan2_k<<<1, 256, 0, stream>>>(part, nblk);
    scan3_k<<<nblk, 256, 0, stream>>>(rowptr, part, cursor, N, E);
    scatter_k<<<(E + 255) / 256, 256, 0, stream>>>(ei, cursor, pos, csr_src, E);

    for (int l = 0; l < 3; l++) {
        const float* Ain = (l == 0) ? x : hbuf[l - 1];
        gemm128<<<(N + 63) / 64, 256, 0, stream>>>(Ain, W[l], xs, N);
        node_al<<<(N * 8 + 255) / 256, 256, 0, stream>>>(xs, as_[l], ad_[l], alsrc, aldst, N);
        aew_k<<<1, 128, 0, stream>>>(We[l], ae_[l], aeW);
        ale_k<<<(E + 255) / 256, 256, 0, stream>>>(ei, eattr, alsrc, aeW, pos, ale, E);
        gather_k<<<(N + 3) / 4, 256, 0, stream>>>(rowptr, csr_src, ale, aldst, xs,
                                                  b_[l], hbuf[l], N);
    }
    hipMemsetAsync(pool, 0, (size_t)G * 128 * sizeof(float), stream);
    pool_k<<<(N * 128 + 255) / 256, 256, 0, stream>>>(hbuf[2], batch, pool, N);

    init_out<<<(N + 255) / 256, 256, 0, stream>>>((float*)d_out, bl2, N);
    dim3 fg((N + 63) / 64, 2);
    final_mfma<<<fg, 256, 0, stream>>>(hbuf[0], hbuf[1], hbuf[2], pool, batch,
                                       wl1t, bl1, Wl2, (float*)d_out, N);
}